// Round 3
// baseline (223.998 us; speedup 1.0000x reference)
//
#include <hip/hip_runtime.h>
#include <hip/hip_bf16.h>
#include <stdint.h>

#define HIDDEN 128

typedef __attribute__((ext_vector_type(8))) short bf16x8;
typedef __attribute__((ext_vector_type(4))) float f32x4;

// round-to-nearest-even f32 -> bf16 bits
static __device__ __forceinline__ unsigned short f2bf(float f) {
    union { float f; uint32_t u; } v; v.f = f;
    uint32_t u = v.u;
    uint32_t r = (u + 0x7fffu + ((u >> 16) & 1u)) >> 16;
    return (unsigned short)r;
}
static __device__ __forceinline__ float bf_lo(uint32_t p) {
    union { uint32_t u; float f; } v; v.u = p << 16; return v.f;
}
static __device__ __forceinline__ float bf_hi(uint32_t p) {
    union { uint32_t u; float f; } v; v.u = p & 0xffff0000u; return v.f;
}
static __device__ __forceinline__ bf16x8 pack8(float4 a, float4 b) {
    bf16x8 r;
    r[0] = (short)f2bf(a.x); r[1] = (short)f2bf(a.y);
    r[2] = (short)f2bf(a.z); r[3] = (short)f2bf(a.w);
    r[4] = (short)f2bf(b.x); r[5] = (short)f2bf(b.y);
    r[6] = (short)f2bf(b.z); r[7] = (short)f2bf(b.w);
    return r;
}

// MFMA GEMM: UV[n][c] = sum_k z[n][k] * B[k][c]  (+ b1[c] for c<128)
//   B[k][c] = W1[k + 128*(c>=128)][c & 127]
// B staged in LDS column-major Blds[c][128 k], bf16, XOR-swizzled:
//   element index within column = k ^ ((c & 15) << 3)
// Operand-swapped MFMA: A = W-fragment (16 c's x 32 k), B = z-fragment
// (32 k x 16 nodes) => D[c][node]; lane then owns 4 CONSECUTIVE c for one
// node -> single ushort4 (8 B) store per subtile.
// Each wave: 32 nodes (2 subgroups of 16); block = 4 waves = 128-node tile.
__global__ __launch_bounds__(256, 2) void precompute_mfma(
    const float* __restrict__ z, const float* __restrict__ W1,
    const float* __restrict__ b1,
    unsigned short* __restrict__ UV, int n_nodes, int n_tiles)
{
    __shared__ unsigned short Blds[256 * 128];  // 64 KB

    const int tid = threadIdx.x;

    // ---- stage B (fp32 W1 -> bf16, swizzled) ----
    for (int cid = tid; cid < 4096; cid += 256) {
        const int r2 = cid & 127;
        const int j4 = cid >> 7;
        const int r = r2 * 2;
        const float4 w0  = *reinterpret_cast<const float4*>(W1 + (size_t)r * 128 + j4 * 4);
        const float4 w1r = *reinterpret_cast<const float4*>(W1 + (size_t)(r + 1) * 128 + j4 * 4);
        const int k = r & 127;                      // even
        const int chalf = (r >= 128) ? 128 : 0;
        #pragma unroll
        for (int cc = 0; cc < 4; ++cc) {
            const int c = chalf + j4 * 4 + cc;
            const uint32_t lo = f2bf((&w0.x)[cc]);
            const uint32_t hi = f2bf((&w1r.x)[cc]);
            const int idx = c * 128 + (k ^ ((c & 15) << 3));
            *reinterpret_cast<uint32_t*>(&Blds[idx]) = lo | (hi << 16);
        }
    }
    __syncthreads();

    const int lane = tid & 63;
    const int wv = tid >> 6;
    const int lg = lane >> 4;   // k-block / D-row group
    const int lr = lane & 15;   // c within A-subtile / node within D

    for (int tile = blockIdx.x; tile < n_tiles; tile += gridDim.x) {
        const int nbase = tile * 128 + wv * 32;

        // load + pack z fragments for 2 node subgroups (B-operand layout:
        // col=lane&15 -> node, k=(lane>>4)*8+j)
        bf16x8 afr[2][4];
        #pragma unroll
        for (int sub = 0; sub < 2; ++sub) {
            int row = nbase + sub * 16 + lr;
            row = (row < n_nodes) ? row : (n_nodes - 1);
            const float* zrow = z + (size_t)row * HIDDEN;
            #pragma unroll
            for (int ks = 0; ks < 4; ++ks) {
                const float4 a = *reinterpret_cast<const float4*>(zrow + ks * 32 + lg * 8);
                const float4 b = *reinterpret_cast<const float4*>(zrow + ks * 32 + lg * 8 + 4);
                afr[sub][ks] = pack8(a, b);
            }
        }

        f32x4 acc[2][16];
        #pragma unroll
        for (int sub = 0; sub < 2; ++sub)
            #pragma unroll
            for (int ns = 0; ns < 16; ++ns)
                acc[sub][ns] = (f32x4){0.f, 0.f, 0.f, 0.f};

        #pragma unroll
        for (int ns = 0; ns < 16; ++ns) {
            const int c = ns * 16 + lr;
            #pragma unroll
            for (int ks = 0; ks < 4; ++ks) {
                const bf16x8 bfr = *reinterpret_cast<const bf16x8*>(
                    &Blds[c * 128 + ((ks * 32 + lg * 8) ^ (lr << 3))]);
                acc[0][ns] = __builtin_amdgcn_mfma_f32_16x16x32_bf16(bfr, afr[0][ks], acc[0][ns], 0, 0, 0);
                acc[1][ns] = __builtin_amdgcn_mfma_f32_16x16x32_bf16(bfr, afr[1][ks], acc[1][ns], 0, 0, 0);
            }
        }

        // store: D col=lane&15 -> node = nbase+sub*16+lr;
        //        D row=lg*4+rr -> c = ns*16+lg*4+rr  (4 consecutive c per lane)
        #pragma unroll
        for (int ns = 0; ns < 16; ++ns) {
            float4 badd = {0.f, 0.f, 0.f, 0.f};
            if (ns < 8)   // compile-time after unroll: u-half gets b1 folded in
                badd = *reinterpret_cast<const float4*>(b1 + ns * 16 + lg * 4);
            #pragma unroll
            for (int sub = 0; sub < 2; ++sub) {
                const int node = nbase + sub * 16 + lr;
                if (node < n_nodes) {
                    ushort4 sv;
                    sv.x = f2bf(acc[sub][ns][0] + badd.x);
                    sv.y = f2bf(acc[sub][ns][1] + badd.y);
                    sv.z = f2bf(acc[sub][ns][2] + badd.z);
                    sv.w = f2bf(acc[sub][ns][3] + badd.w);
                    *reinterpret_cast<ushort4*>(UV + (uint32_t)node * 256u + ns * 16 + lg * 4) = sv;
                }
            }
        }
    }
}

// score[e] = sum_j relu(u'[src][j] + v[dst][j]) * W2[j] + b2   (u' has b1)
// 16 lanes per edge, 4 edges per lane-group (batched for MLP).
static __device__ __forceinline__ float dot8(uint4 u, uint4 v, float4 wa, float4 wb) {
    const uint32_t up[4] = { u.x, u.y, u.z, u.w };
    const uint32_t vp[4] = { v.x, v.y, v.z, v.w };
    const float w[8] = { wa.x, wa.y, wa.z, wa.w, wb.x, wb.y, wb.z, wb.w };
    float s = 0.f;
    #pragma unroll
    for (int p = 0; p < 4; ++p) {
        const float h0 = bf_lo(up[p]) + bf_lo(vp[p]);
        const float h1 = bf_hi(up[p]) + bf_hi(vp[p]);
        s = fmaf(fmaxf(h0, 0.f), w[2 * p], s);
        s = fmaf(fmaxf(h1, 0.f), w[2 * p + 1], s);
    }
    return s;
}

__global__ __launch_bounds__(256) void edge_score(
    const int* __restrict__ ei, const unsigned short* __restrict__ UV,
    const float* __restrict__ W2, const float* __restrict__ b2,
    float* __restrict__ out, int n_edges)
{
    const int g = (blockIdx.x * 256 + threadIdx.x) >> 4;
    const int q = threadIdx.x & 15;
    const int e0 = g * 4;
    if (e0 >= n_edges) return;

    const float4 w2a = *reinterpret_cast<const float4*>(W2 + q * 8);
    const float4 w2b = *reinterpret_cast<const float4*>(W2 + q * 8 + 4);
    const float bias = b2[0];

    const char* UVb = (const char*)UV;
    const uint32_t qo = (uint32_t)q * 16u;

    if (e0 + 3 < n_edges) {
        const int4 s4 = *reinterpret_cast<const int4*>(ei + e0);
        const int4 d4 = *reinterpret_cast<const int4*>(ei + n_edges + e0);

        const uint4 u0 = *reinterpret_cast<const uint4*>(UVb + ((uint32_t)s4.x * 512u + qo));
        const uint4 v0 = *reinterpret_cast<const uint4*>(UVb + ((uint32_t)d4.x * 512u + 256u + qo));
        const uint4 u1 = *reinterpret_cast<const uint4*>(UVb + ((uint32_t)s4.y * 512u + qo));
        const uint4 v1 = *reinterpret_cast<const uint4*>(UVb + ((uint32_t)d4.y * 512u + 256u + qo));
        const uint4 u2 = *reinterpret_cast<const uint4*>(UVb + ((uint32_t)s4.z * 512u + qo));
        const uint4 v2 = *reinterpret_cast<const uint4*>(UVb + ((uint32_t)d4.z * 512u + 256u + qo));
        const uint4 u3 = *reinterpret_cast<const uint4*>(UVb + ((uint32_t)s4.w * 512u + qo));
        const uint4 v3 = *reinterpret_cast<const uint4*>(UVb + ((uint32_t)d4.w * 512u + 256u + qo));

        float s0 = dot8(u0, v0, w2a, w2b);
        float s1 = dot8(u1, v1, w2a, w2b);
        float s2 = dot8(u2, v2, w2a, w2b);
        float s3 = dot8(u3, v3, w2a, w2b);

        s0 += __shfl_xor(s0, 1, 64); s0 += __shfl_xor(s0, 2, 64);
        s0 += __shfl_xor(s0, 4, 64); s0 += __shfl_xor(s0, 8, 64);
        s1 += __shfl_xor(s1, 1, 64); s1 += __shfl_xor(s1, 2, 64);
        s1 += __shfl_xor(s1, 4, 64); s1 += __shfl_xor(s1, 8, 64);
        s2 += __shfl_xor(s2, 1, 64); s2 += __shfl_xor(s2, 2, 64);
        s2 += __shfl_xor(s2, 4, 64); s2 += __shfl_xor(s2, 8, 64);
        s3 += __shfl_xor(s3, 1, 64); s3 += __shfl_xor(s3, 2, 64);
        s3 += __shfl_xor(s3, 4, 64); s3 += __shfl_xor(s3, 8, 64);

        if (q == 0) {
            float4 o = { s0 + bias, s1 + bias, s2 + bias, s3 + bias };
            *reinterpret_cast<float4*>(out + e0) = o;
        }
    } else {
        for (int i = 0; i < 4; ++i) {
            const int e = e0 + i;
            if (e >= n_edges) break;
            const int sidx = ei[e];
            const int didx = ei[n_edges + e];
            const uint4 uu = *reinterpret_cast<const uint4*>(UVb + ((uint32_t)sidx * 512u + qo));
            const uint4 vv = *reinterpret_cast<const uint4*>(UVb + ((uint32_t)didx * 512u + 256u + qo));
            float s = dot8(uu, vv, w2a, w2b);
            s += __shfl_xor(s, 1, 64); s += __shfl_xor(s, 2, 64);
            s += __shfl_xor(s, 4, 64); s += __shfl_xor(s, 8, 64);
            if (q == 0) out[e] = s + bias;
        }
    }
}

extern "C" void kernel_launch(void* const* d_in, const int* in_sizes, int n_in,
                              void* d_out, int out_size, void* d_ws, size_t ws_size,
                              hipStream_t stream) {
    const float* z  = (const float*)d_in[0];
    const int*   ei = (const int*)d_in[1];
    const float* W1 = (const float*)d_in[2];
    const float* b1 = (const float*)d_in[3];
    const float* W2 = (const float*)d_in[4];
    const float* b2 = (const float*)d_in[5];
    float* out = (float*)d_out;

    const int n_nodes = in_sizes[0] / HIDDEN;
    const int n_edges = in_sizes[1] / 2;

    unsigned short* UV = (unsigned short*)d_ws;  // [n_nodes][256] bf16, b1 folded into u-half

    // Kernel 1: per-node u/v via bf16 MFMA GEMM (128 rows per block-iteration)
    {
        const int n_tiles = (n_nodes + 127) / 128;
        const int g1 = n_tiles < 512 ? n_tiles : 512;  // 2 blocks/CU (64 KB LDS each)
        precompute_mfma<<<g1, 256, 0, stream>>>(z, W1, b1, UV, n_nodes, n_tiles);
    }
    // Kernel 2: per-edge score, 4 edges per 16-lane group
    {
        const int groups = (n_edges + 3) / 4;
        const int blocks = (groups * 16 + 255) / 256;
        edge_score<<<blocks, 256, 0, stream>>>(ei, UV, W2, b2, out, n_edges);
    }
}

// Round 4
// 159.140 us; speedup vs baseline: 1.4076x; 1.4076x over previous
//
#include <hip/hip_runtime.h>
#include <hip/hip_bf16.h>
#include <stdint.h>

#define HIDDEN 128

typedef __attribute__((ext_vector_type(8))) short bf16x8;
typedef __attribute__((ext_vector_type(16))) float f32x16;

// round-to-nearest-even f32 -> bf16 bits
static __device__ __forceinline__ unsigned short f2bf(float f) {
    union { float f; uint32_t u; } v; v.f = f;
    uint32_t u = v.u;
    uint32_t r = (u + 0x7fffu + ((u >> 16) & 1u)) >> 16;
    return (unsigned short)r;
}
static __device__ __forceinline__ float bf_lo(uint32_t p) {
    union { uint32_t u; float f; } v; v.u = p << 16; return v.f;
}
static __device__ __forceinline__ float bf_hi(uint32_t p) {
    union { uint32_t u; float f; } v; v.u = p & 0xffff0000u; return v.f;
}
static __device__ __forceinline__ bf16x8 pack8(float4 a, float4 b) {
    bf16x8 r;
    r[0] = (short)f2bf(a.x); r[1] = (short)f2bf(a.y);
    r[2] = (short)f2bf(a.z); r[3] = (short)f2bf(a.w);
    r[4] = (short)f2bf(b.x); r[5] = (short)f2bf(b.y);
    r[6] = (short)f2bf(b.z); r[7] = (short)f2bf(b.w);
    return r;
}

// UV[n][cc] = sum_k z[n][k] * Bm[k][cc] (+ b1[cc] for cc<128)
//   Bm[k][cc] = W1[k + 128*(cc>=128)][cc & 127]
// mfma_f32_32x32x16_bf16, A = W-fragment (rows = cc), B = z-fragment
// (cols = node). No LDS, no barriers. Wave w owns cc in [w*64, w*64+64).
// W fragments live in VGPRs for the whole kernel (loaded once per block).
// D layout: col = lane&31 -> node; row = (reg&3) + 8*(reg>>2) + 4*(lane>>5)
// -> cc offset. Four g-stores (ushort4) cover each node's 64-B line fully.
__global__ __launch_bounds__(256) void precompute_mfma32(
    const float* __restrict__ z, const float* __restrict__ W1,
    const float* __restrict__ b1,
    unsigned short* __restrict__ UV, int n_nodes, int n_groups)
{
    const int lane = threadIdx.x & 63;
    const int w = threadIdx.x >> 6;     // wave id 0..3 -> cc base w*64
    const int nl = lane & 31;           // node lane / cc lane
    const int hi = lane >> 5;           // k-half (k = ks*16 + hi*8 + j)

    // ---- W fragments (A-operand), loaded once ----
    bf16x8 wf[2][8];
    #pragma unroll
    for (int cg = 0; cg < 2; ++cg) {
        const int cc = w * 64 + cg * 32 + nl;
        const int ccol = cc & 127;
        const int kofs = (cc >= 128) ? 128 : 0;
        #pragma unroll
        for (int ks = 0; ks < 8; ++ks) {
            const int k0 = ks * 16 + hi * 8 + kofs;
            float a[8];
            #pragma unroll
            for (int j = 0; j < 8; ++j)
                a[j] = W1[(size_t)(k0 + j) * 128 + ccol];
            bf16x8 f;
            #pragma unroll
            for (int j = 0; j < 8; ++j) f[j] = (short)f2bf(a[j]);
            wf[cg][ks] = f;
        }
    }

    // ---- accumulator init = b1 (u-half) or 0 (v-half) ----
    f32x16 binit[2];
    #pragma unroll
    for (int cg = 0; cg < 2; ++cg) {
        const int cc0 = w * 64 + cg * 32;
        #pragma unroll
        for (int r = 0; r < 16; ++r) {
            const int crow = (r & 3) + 8 * (r >> 2) + 4 * hi;
            const int cc = cc0 + crow;
            binit[cg][r] = (cc < 128) ? b1[cc] : 0.f;
        }
    }

    for (int ng = blockIdx.x; ng < n_groups; ng += gridDim.x) {
        const int node = ng * 32 + nl;
        const int nc = (node < n_nodes) ? node : (n_nodes - 1);
        const float* zrow = z + (size_t)nc * HIDDEN;

        // z fragments (B-operand): lane's node = nl, k = ks*16 + hi*8 + j
        bf16x8 zf[8];
        #pragma unroll
        for (int ks = 0; ks < 8; ++ks) {
            const float4 a = *reinterpret_cast<const float4*>(zrow + ks * 16 + hi * 8);
            const float4 b = *reinterpret_cast<const float4*>(zrow + ks * 16 + hi * 8 + 4);
            zf[ks] = pack8(a, b);
        }

        f32x16 acc0 = binit[0];
        f32x16 acc1 = binit[1];
        #pragma unroll
        for (int ks = 0; ks < 8; ++ks) {
            acc0 = __builtin_amdgcn_mfma_f32_32x32x16_bf16(wf[0][ks], zf[ks], acc0, 0, 0, 0);
            acc1 = __builtin_amdgcn_mfma_f32_32x32x16_bf16(wf[1][ks], zf[ks], acc1, 0, 0, 0);
        }

        if (node < n_nodes) {
            unsigned short* orow = UV + (size_t)node * 256;
            #pragma unroll
            for (int cg = 0; cg < 2; ++cg) {
                const f32x16 A = cg ? acc1 : acc0;
                #pragma unroll
                for (int g = 0; g < 4; ++g) {
                    ushort4 sv;
                    sv.x = f2bf(A[4 * g + 0]);
                    sv.y = f2bf(A[4 * g + 1]);
                    sv.z = f2bf(A[4 * g + 2]);
                    sv.w = f2bf(A[4 * g + 3]);
                    *reinterpret_cast<ushort4*>(orow + w * 64 + cg * 32 + g * 8 + hi * 4) = sv;
                }
            }
        }
    }
}

// score[e] = sum_j relu(u'[src][j] + v[dst][j]) * W2[j] + b2   (u' has b1)
// 16 lanes per edge, 8 edges per lane-group.
static __device__ __forceinline__ float dot8(uint4 u, uint4 v, const float* w) {
    const uint32_t up[4] = { u.x, u.y, u.z, u.w };
    const uint32_t vp[4] = { v.x, v.y, v.z, v.w };
    float s = 0.f;
    #pragma unroll
    for (int p = 0; p < 4; ++p) {
        const float h0 = bf_lo(up[p]) + bf_lo(vp[p]);
        const float h1 = bf_hi(up[p]) + bf_hi(vp[p]);
        s = fmaf(fmaxf(h0, 0.f), w[2 * p], s);
        s = fmaf(fmaxf(h1, 0.f), w[2 * p + 1], s);
    }
    return s;
}
static __device__ __forceinline__ float red16(float s) {
    s += __shfl_xor(s, 1, 64); s += __shfl_xor(s, 2, 64);
    s += __shfl_xor(s, 4, 64); s += __shfl_xor(s, 8, 64);
    return s;
}

__global__ __launch_bounds__(256) void edge_score(
    const int* __restrict__ ei, const unsigned short* __restrict__ UV,
    const float* __restrict__ W2, const float* __restrict__ b2,
    float* __restrict__ out, int n_edges)
{
    const int g = (blockIdx.x * 256 + threadIdx.x) >> 4;
    const int q = threadIdx.x & 15;
    const int e0 = g * 8;
    if (e0 >= n_edges) return;

    const float4 w2a = *reinterpret_cast<const float4*>(W2 + q * 8);
    const float4 w2b = *reinterpret_cast<const float4*>(W2 + q * 8 + 4);
    const float wloc[8] = { w2a.x, w2a.y, w2a.z, w2a.w, w2b.x, w2b.y, w2b.z, w2b.w };
    const float bias = b2[0];

    const char* UVb = (const char*)UV;
    const uint32_t qo = (uint32_t)q * 16u;

    if (e0 + 7 < n_edges) {
        const int4 sA = *reinterpret_cast<const int4*>(ei + e0);
        const int4 sB = *reinterpret_cast<const int4*>(ei + e0 + 4);
        const int4 dA = *reinterpret_cast<const int4*>(ei + n_edges + e0);
        const int4 dB = *reinterpret_cast<const int4*>(ei + n_edges + e0 + 4);
        const int sidx[8] = { sA.x, sA.y, sA.z, sA.w, sB.x, sB.y, sB.z, sB.w };
        const int didx[8] = { dA.x, dA.y, dA.z, dA.w, dB.x, dB.y, dB.z, dB.w };

        uint4 u[8], v[8];
        #pragma unroll
        for (int i = 0; i < 8; ++i) {
            u[i] = *reinterpret_cast<const uint4*>(UVb + ((uint32_t)sidx[i] * 512u + qo));
            v[i] = *reinterpret_cast<const uint4*>(UVb + ((uint32_t)didx[i] * 512u + 256u + qo));
        }

        float s[8];
        #pragma unroll
        for (int i = 0; i < 8; ++i) s[i] = dot8(u[i], v[i], wloc);
        #pragma unroll
        for (int i = 0; i < 8; ++i) s[i] = red16(s[i]);

        if (q == 0) {
            float4 oA = { s[0] + bias, s[1] + bias, s[2] + bias, s[3] + bias };
            float4 oB = { s[4] + bias, s[5] + bias, s[6] + bias, s[7] + bias };
            *reinterpret_cast<float4*>(out + e0) = oA;
            *reinterpret_cast<float4*>(out + e0 + 4) = oB;
        }
    } else {
        for (int i = 0; i < 8; ++i) {
            const int e = e0 + i;
            if (e >= n_edges) break;
            const int si = ei[e];
            const int di = ei[n_edges + e];
            const uint4 uu = *reinterpret_cast<const uint4*>(UVb + ((uint32_t)si * 512u + qo));
            const uint4 vv = *reinterpret_cast<const uint4*>(UVb + ((uint32_t)di * 512u + 256u + qo));
            float s = red16(dot8(uu, vv, wloc));
            if (q == 0) out[e] = s + bias;
        }
    }
}

extern "C" void kernel_launch(void* const* d_in, const int* in_sizes, int n_in,
                              void* d_out, int out_size, void* d_ws, size_t ws_size,
                              hipStream_t stream) {
    const float* z  = (const float*)d_in[0];
    const int*   ei = (const int*)d_in[1];
    const float* W1 = (const float*)d_in[2];
    const float* b1 = (const float*)d_in[3];
    const float* W2 = (const float*)d_in[4];
    const float* b2 = (const float*)d_in[5];
    float* out = (float*)d_out;

    const int n_nodes = in_sizes[0] / HIDDEN;
    const int n_edges = in_sizes[1] / 2;

    unsigned short* UV = (unsigned short*)d_ws;  // [n_nodes][256] bf16, b1 folded into u-half

    // Kernel 1: per-node u/v via register-resident-W 32x32x16 MFMA, no LDS
    {
        const int n_groups = (n_nodes + 31) / 32;
        const int g1 = n_groups < 512 ? n_groups : 512;
        precompute_mfma32<<<g1, 256, 0, stream>>>(z, W1, b1, UV, n_nodes, n_groups);
    }
    // Kernel 2: per-edge score, 8 edges per 16-lane group
    {
        const int groups = (n_edges + 7) / 8;
        const int blocks = (groups * 16 + 255) / 256;
        edge_score<<<blocks, 256, 0, stream>>>(ei, UV, W2, b2, out, n_edges);
    }
}

// Round 5
// 155.206 us; speedup vs baseline: 1.4432x; 1.0253x over previous
//
#include <hip/hip_runtime.h>
#include <hip/hip_bf16.h>
#include <stdint.h>

#define HIDDEN 128

typedef __attribute__((ext_vector_type(8))) short bf16x8;
typedef __attribute__((ext_vector_type(16))) float f32x16;

// round-to-nearest-even f32 -> bf16 bits
static __device__ __forceinline__ unsigned short f2bf(float f) {
    union { float f; uint32_t u; } v; v.f = f;
    uint32_t u = v.u;
    uint32_t r = (u + 0x7fffu + ((u >> 16) & 1u)) >> 16;
    return (unsigned short)r;
}
static __device__ __forceinline__ float bf_lo(uint32_t p) {
    union { uint32_t u; float f; } v; v.u = p << 16; return v.f;
}
static __device__ __forceinline__ float bf_hi(uint32_t p) {
    union { uint32_t u; float f; } v; v.u = p & 0xffff0000u; return v.f;
}
static __device__ __forceinline__ bf16x8 pack8(float4 a, float4 b) {
    bf16x8 r;
    r[0] = (short)f2bf(a.x); r[1] = (short)f2bf(a.y);
    r[2] = (short)f2bf(a.z); r[3] = (short)f2bf(a.w);
    r[4] = (short)f2bf(b.x); r[5] = (short)f2bf(b.y);
    r[6] = (short)f2bf(b.z); r[7] = (short)f2bf(b.w);
    return r;
}

// ---------------- precompute: UV = z @ Bm (+b1 on u-half) ----------------
// mfma_f32_32x32x16_bf16, A = W-fragment (rows = cc), B = z-fragment
// (cols = node). No LDS, no barriers. Wave w owns cc in [w*64, w*64+64).
// W fragments live in VGPRs for the whole kernel. 2-deep z prefetch
// pipeline (statically-named ping-pong buffers).

struct ZBuf { float4 a[8], b[8]; };  // raw fp32 z for one node, ks=0..7

static __device__ __forceinline__ void load_z(ZBuf& zb, const float* __restrict__ z,
                                              int ng, int nl, int hi, int n_nodes) {
    int node = ng * 32 + nl;
    node = (node < n_nodes) ? node : (n_nodes - 1);
    const float* zrow = z + (size_t)node * HIDDEN;
    #pragma unroll
    for (int ks = 0; ks < 8; ++ks) {
        zb.a[ks] = *reinterpret_cast<const float4*>(zrow + ks * 16 + hi * 8);
        zb.b[ks] = *reinterpret_cast<const float4*>(zrow + ks * 16 + hi * 8 + 4);
    }
}

static __device__ __forceinline__ void compute_store(
    const ZBuf& zb, const bf16x8 (&wf)[2][8], const f32x16 (&binit)[2],
    unsigned short* __restrict__ UV, int ng, int nl, int hi, int w, int n_nodes)
{
    bf16x8 zf[8];
    #pragma unroll
    for (int ks = 0; ks < 8; ++ks) zf[ks] = pack8(zb.a[ks], zb.b[ks]);

    f32x16 acc0 = binit[0];
    f32x16 acc1 = binit[1];
    #pragma unroll
    for (int ks = 0; ks < 8; ++ks) {
        acc0 = __builtin_amdgcn_mfma_f32_32x32x16_bf16(wf[0][ks], zf[ks], acc0, 0, 0, 0);
        acc1 = __builtin_amdgcn_mfma_f32_32x32x16_bf16(wf[1][ks], zf[ks], acc1, 0, 0, 0);
    }

    const int node = ng * 32 + nl;
    if (node < n_nodes) {
        unsigned short* orow = UV + (size_t)node * 256;
        #pragma unroll
        for (int g = 0; g < 4; ++g) {
            ushort4 s0, s1;
            s0.x = f2bf(acc0[4 * g + 0]); s0.y = f2bf(acc0[4 * g + 1]);
            s0.z = f2bf(acc0[4 * g + 2]); s0.w = f2bf(acc0[4 * g + 3]);
            s1.x = f2bf(acc1[4 * g + 0]); s1.y = f2bf(acc1[4 * g + 1]);
            s1.z = f2bf(acc1[4 * g + 2]); s1.w = f2bf(acc1[4 * g + 3]);
            *reinterpret_cast<ushort4*>(orow + w * 64 + g * 8 + hi * 4) = s0;
            *reinterpret_cast<ushort4*>(orow + w * 64 + 32 + g * 8 + hi * 4) = s1;
        }
    }
}

__global__ __launch_bounds__(256) void precompute_mfma32(
    const float* __restrict__ z, const float* __restrict__ W1,
    const float* __restrict__ b1,
    unsigned short* __restrict__ UV, int n_nodes, int n_groups)
{
    const int lane = threadIdx.x & 63;
    const int w = threadIdx.x >> 6;     // wave id 0..3 -> cc base w*64
    const int nl = lane & 31;           // node lane / cc lane
    const int hi = lane >> 5;           // k-half (k = ks*16 + hi*8 + j)

    // ---- W fragments (A-operand), loaded once ----
    bf16x8 wf[2][8];
    #pragma unroll
    for (int cg = 0; cg < 2; ++cg) {
        const int cc = w * 64 + cg * 32 + nl;
        const int ccol = cc & 127;
        const int kofs = (cc >= 128) ? 128 : 0;
        #pragma unroll
        for (int ks = 0; ks < 8; ++ks) {
            const int k0 = ks * 16 + hi * 8 + kofs;
            bf16x8 f;
            #pragma unroll
            for (int j = 0; j < 8; ++j)
                f[j] = (short)f2bf(W1[(size_t)(k0 + j) * 128 + ccol]);
            wf[cg][ks] = f;
        }
    }

    // ---- accumulator init = b1 (u-half) or 0 (v-half) ----
    f32x16 binit[2];
    #pragma unroll
    for (int cg = 0; cg < 2; ++cg) {
        const int cc0 = w * 64 + cg * 32;
        #pragma unroll
        for (int r = 0; r < 16; ++r) {
            const int crow = (r & 3) + 8 * (r >> 2) + 4 * hi;
            const int cc = cc0 + crow;
            binit[cg][r] = (cc < 128) ? b1[cc] : 0.f;
        }
    }

    const int stride = gridDim.x;
    int ng = blockIdx.x;
    if (ng >= n_groups) return;

    ZBuf bufA, bufB;
    load_z(bufA, z, ng, nl, hi, n_nodes);

    while (ng < n_groups) {
        const int n1 = ng + stride;
        if (n1 < n_groups) load_z(bufB, z, n1, nl, hi, n_nodes);
        compute_store(bufA, wf, binit, UV, ng, nl, hi, w, n_nodes);
        if (n1 >= n_groups) break;

        const int n2 = n1 + stride;
        if (n2 < n_groups) load_z(bufA, z, n2, nl, hi, n_nodes);
        compute_store(bufB, wf, binit, UV, n1, nl, hi, w, n_nodes);
        ng = n2;
    }
}

// ---------------- edge scoring ----------------
// score[e] = sum_j relu(u'[src][j] + v[dst][j]) * W2[j] + b2   (u' has b1)
// 16 lanes per edge, 12 edges per lane-group (deep MLP, VGPR <= ~128).
static __device__ __forceinline__ float dot8(uint4 u, uint4 v, const float* w) {
    const uint32_t up[4] = { u.x, u.y, u.z, u.w };
    const uint32_t vp[4] = { v.x, v.y, v.z, v.w };
    float s = 0.f;
    #pragma unroll
    for (int p = 0; p < 4; ++p) {
        const float h0 = bf_lo(up[p]) + bf_lo(vp[p]);
        const float h1 = bf_hi(up[p]) + bf_hi(vp[p]);
        s = fmaf(fmaxf(h0, 0.f), w[2 * p], s);
        s = fmaf(fmaxf(h1, 0.f), w[2 * p + 1], s);
    }
    return s;
}
static __device__ __forceinline__ float red16(float s) {
    s += __shfl_xor(s, 1, 64); s += __shfl_xor(s, 2, 64);
    s += __shfl_xor(s, 4, 64); s += __shfl_xor(s, 8, 64);
    return s;
}

#define EPG 12  // edges per 16-lane group

__global__ __launch_bounds__(256) void edge_score(
    const int* __restrict__ ei, const unsigned short* __restrict__ UV,
    const float* __restrict__ W2, const float* __restrict__ b2,
    float* __restrict__ out, int n_edges)
{
    const int g = (blockIdx.x * 256 + threadIdx.x) >> 4;
    const int q = threadIdx.x & 15;
    const int e0 = g * EPG;
    if (e0 >= n_edges) return;

    const float4 w2a = *reinterpret_cast<const float4*>(W2 + q * 8);
    const float4 w2b = *reinterpret_cast<const float4*>(W2 + q * 8 + 4);
    const float wloc[8] = { w2a.x, w2a.y, w2a.z, w2a.w, w2b.x, w2b.y, w2b.z, w2b.w };
    const float bias = b2[0];

    const char* UVb = (const char*)UV;
    const uint32_t qo = (uint32_t)q * 16u;

    if (e0 + EPG - 1 < n_edges) {
        int sidx[EPG], didx[EPG];
        #pragma unroll
        for (int c = 0; c < EPG / 4; ++c) {
            const int4 s4 = *reinterpret_cast<const int4*>(ei + e0 + 4 * c);
            const int4 d4 = *reinterpret_cast<const int4*>(ei + n_edges + e0 + 4 * c);
            sidx[4 * c + 0] = s4.x; sidx[4 * c + 1] = s4.y;
            sidx[4 * c + 2] = s4.z; sidx[4 * c + 3] = s4.w;
            didx[4 * c + 0] = d4.x; didx[4 * c + 1] = d4.y;
            didx[4 * c + 2] = d4.z; didx[4 * c + 3] = d4.w;
        }

        uint4 u[EPG], v[EPG];
        #pragma unroll
        for (int i = 0; i < EPG; ++i) {
            u[i] = *reinterpret_cast<const uint4*>(UVb + ((uint32_t)sidx[i] * 512u + qo));
            v[i] = *reinterpret_cast<const uint4*>(UVb + ((uint32_t)didx[i] * 512u + 256u + qo));
        }

        float s[EPG];
        #pragma unroll
        for (int i = 0; i < EPG; ++i) s[i] = dot8(u[i], v[i], wloc);
        #pragma unroll
        for (int i = 0; i < EPG; ++i) s[i] = red16(s[i]) + bias;

        if (q == 0) {
            #pragma unroll
            for (int c = 0; c < EPG / 4; ++c) {
                float4 o = { s[4 * c], s[4 * c + 1], s[4 * c + 2], s[4 * c + 3] };
                *reinterpret_cast<float4*>(out + e0 + 4 * c) = o;
            }
        }
    } else {
        for (int i = 0; i < EPG; ++i) {
            const int e = e0 + i;
            if (e >= n_edges) break;
            const int si = ei[e];
            const int di = ei[n_edges + e];
            const uint4 uu = *reinterpret_cast<const uint4*>(UVb + ((uint32_t)si * 512u + qo));
            const uint4 vv = *reinterpret_cast<const uint4*>(UVb + ((uint32_t)di * 512u + 256u + qo));
            float s = red16(dot8(uu, vv, wloc));
            if (q == 0) out[e] = s + bias;
        }
    }
}

extern "C" void kernel_launch(void* const* d_in, const int* in_sizes, int n_in,
                              void* d_out, int out_size, void* d_ws, size_t ws_size,
                              hipStream_t stream) {
    const float* z  = (const float*)d_in[0];
    const int*   ei = (const int*)d_in[1];
    const float* W1 = (const float*)d_in[2];
    const float* b1 = (const float*)d_in[3];
    const float* W2 = (const float*)d_in[4];
    const float* b2 = (const float*)d_in[5];
    float* out = (float*)d_out;

    const int n_nodes = in_sizes[0] / HIDDEN;
    const int n_edges = in_sizes[1] / 2;

    unsigned short* UV = (unsigned short*)d_ws;  // [n_nodes][256] bf16, b1 folded into u-half

    // Kernel 1: per-node u/v via register-resident-W 32x32x16 MFMA, no LDS,
    // 2-deep z prefetch pipeline
    {
        const int n_groups = (n_nodes + 31) / 32;
        const int g1 = n_groups < 512 ? n_groups : 512;
        precompute_mfma32<<<g1, 256, 0, stream>>>(z, W1, b1, UV, n_nodes, n_groups);
    }
    // Kernel 2: per-edge score, 12 edges per 16-lane group
    {
        const int groups = (n_edges + EPG - 1) / EPG;
        const int blocks = (groups * 16 + 255) / 256;
        edge_score<<<blocks, 256, 0, stream>>>(ei, UV, W2, b2, out, n_edges);
    }
}

// Round 6
// 149.115 us; speedup vs baseline: 1.5022x; 1.0409x over previous
//
#include <hip/hip_runtime.h>
#include <hip/hip_bf16.h>
#include <stdint.h>

#define HIDDEN 128

typedef __attribute__((ext_vector_type(8))) short bf16x8;
typedef __attribute__((ext_vector_type(16))) float f32x16;

// round-to-nearest-even f32 -> bf16 bits
static __device__ __forceinline__ unsigned short f2bf(float f) {
    union { float f; uint32_t u; } v; v.f = f;
    uint32_t u = v.u;
    uint32_t r = (u + 0x7fffu + ((u >> 16) & 1u)) >> 16;
    return (unsigned short)r;
}
static __device__ __forceinline__ float bf_lo(uint32_t p) {
    union { uint32_t u; float f; } v; v.u = p << 16; return v.f;
}
static __device__ __forceinline__ float bf_hi(uint32_t p) {
    union { uint32_t u; float f; } v; v.u = p & 0xffff0000u; return v.f;
}
static __device__ __forceinline__ bf16x8 pack8(float4 a, float4 b) {
    bf16x8 r;
    r[0] = (short)f2bf(a.x); r[1] = (short)f2bf(a.y);
    r[2] = (short)f2bf(a.z); r[3] = (short)f2bf(a.w);
    r[4] = (short)f2bf(b.x); r[5] = (short)f2bf(b.y);
    r[6] = (short)f2bf(b.z); r[7] = (short)f2bf(b.w);
    return r;
}

// ---------------- precompute: UV = z @ Bm (+b1 on u-half) ----------------
// mfma_f32_32x32x16_bf16, A = W-fragment (rows = cc), B = z-fragment
// (cols = node). Wave w owns cc in [w*64, w*64+64). W fragments in VGPRs.
// 2-deep z prefetch pipeline. NEW: accumulators staged to LDS (swizzled),
// then cooperatively copied out as full 512-B rows (full-line stores).

struct ZBuf { float4 a[8], b[8]; };  // raw fp32 z for one node-slice

static __device__ __forceinline__ void load_z(ZBuf& zb, const float* __restrict__ z,
                                              int ng, int nl, int hi, int n_nodes) {
    int node = ng * 32 + nl;
    node = (node < n_nodes) ? node : (n_nodes - 1);
    const float* zrow = z + (size_t)node * HIDDEN;
    #pragma unroll
    for (int ks = 0; ks < 8; ++ks) {
        zb.a[ks] = *reinterpret_cast<const float4*>(zrow + ks * 16 + hi * 8);
        zb.b[ks] = *reinterpret_cast<const float4*>(zrow + ks * 16 + hi * 8 + 4);
    }
}

// LDS tile: 32 nodes x 256 cols bf16 = 16 KB. Byte addr for (node, colb):
//   node*512 + (colb ^ ((node & 15) << 3))     (colb multiple of 8)
static __device__ __forceinline__ void compute_to_lds(
    const ZBuf& zb, const bf16x8 (&wf)[2][8], const f32x16 (&binit)[2],
    char* Sm, int nl, int hi, int w)
{
    bf16x8 zf[8];
    #pragma unroll
    for (int ks = 0; ks < 8; ++ks) zf[ks] = pack8(zb.a[ks], zb.b[ks]);

    f32x16 acc0 = binit[0];
    f32x16 acc1 = binit[1];
    #pragma unroll
    for (int ks = 0; ks < 8; ++ks) {
        acc0 = __builtin_amdgcn_mfma_f32_32x32x16_bf16(wf[0][ks], zf[ks], acc0, 0, 0, 0);
        acc1 = __builtin_amdgcn_mfma_f32_32x32x16_bf16(wf[1][ks], zf[ks], acc1, 0, 0, 0);
    }

    const int swz = (nl & 15) << 3;
    #pragma unroll
    for (int g = 0; g < 4; ++g) {
        ushort4 s0, s1;
        s0.x = f2bf(acc0[4 * g + 0]); s0.y = f2bf(acc0[4 * g + 1]);
        s0.z = f2bf(acc0[4 * g + 2]); s0.w = f2bf(acc0[4 * g + 3]);
        s1.x = f2bf(acc1[4 * g + 0]); s1.y = f2bf(acc1[4 * g + 1]);
        s1.z = f2bf(acc1[4 * g + 2]); s1.w = f2bf(acc1[4 * g + 3]);
        const int colb0 = w * 128 + g * 16 + hi * 8;          // cg = 0
        const int colb1 = w * 128 + 64 + g * 16 + hi * 8;     // cg = 1
        *reinterpret_cast<ushort4*>(Sm + nl * 512 + (colb0 ^ swz)) = s0;
        *reinterpret_cast<ushort4*>(Sm + nl * 512 + (colb1 ^ swz)) = s1;
    }
}

static __device__ __forceinline__ void copy_out(
    unsigned short* __restrict__ UV, const char* Sm, int ng, int tid, int n_nodes)
{
    const int colb0 = (tid & 31) * 16;       // 16-B chunk within a 512-B row
    #pragma unroll
    for (int rep = 0; rep < 4; ++rep) {
        const int node_local = rep * 8 + (tid >> 5);
        const int swz = (node_local & 15) << 3;
        const uint2 g0 = *reinterpret_cast<const uint2*>(Sm + node_local * 512 + ((colb0) ^ swz));
        const uint2 g1 = *reinterpret_cast<const uint2*>(Sm + node_local * 512 + ((colb0 + 8) ^ swz));
        const int node = ng * 32 + node_local;
        if (node < n_nodes) {
            uint4 o = { g0.x, g0.y, g1.x, g1.y };
            *reinterpret_cast<uint4*>(UV + (size_t)node * 256 + (tid & 31) * 8) = o;
        }
    }
}

__global__ __launch_bounds__(256) void precompute_mfma32(
    const float* __restrict__ z, const float* __restrict__ W1,
    const float* __restrict__ b1,
    unsigned short* __restrict__ UV, int n_nodes, int n_groups)
{
    __shared__ char Sm[32 * 512];   // 16 KB output staging tile

    const int tid = threadIdx.x;
    const int lane = tid & 63;
    const int w = tid >> 6;
    const int nl = lane & 31;
    const int hi = lane >> 5;

    // ---- W fragments (A-operand), loaded once ----
    bf16x8 wf[2][8];
    #pragma unroll
    for (int cg = 0; cg < 2; ++cg) {
        const int cc = w * 64 + cg * 32 + nl;
        const int ccol = cc & 127;
        const int kofs = (cc >= 128) ? 128 : 0;
        #pragma unroll
        for (int ks = 0; ks < 8; ++ks) {
            const int k0 = ks * 16 + hi * 8 + kofs;
            bf16x8 f;
            #pragma unroll
            for (int j = 0; j < 8; ++j)
                f[j] = (short)f2bf(W1[(size_t)(k0 + j) * 128 + ccol]);
            wf[cg][ks] = f;
        }
    }

    // ---- accumulator init = b1 (u-half) or 0 (v-half) ----
    f32x16 binit[2];
    #pragma unroll
    for (int cg = 0; cg < 2; ++cg) {
        const int cc0 = w * 64 + cg * 32;
        #pragma unroll
        for (int r = 0; r < 16; ++r) {
            const int crow = (r & 3) + 8 * (r >> 2) + 4 * hi;
            const int cc = cc0 + crow;
            binit[cg][r] = (cc < 128) ? b1[cc] : 0.f;
        }
    }

    const int stride = gridDim.x;
    int ng = blockIdx.x;
    if (ng >= n_groups) return;

    ZBuf bufA, bufB;
    load_z(bufA, z, ng, nl, hi, n_nodes);

    while (ng < n_groups) {
        const int n1 = ng + stride;
        if (n1 < n_groups) load_z(bufB, z, n1, nl, hi, n_nodes);
        compute_to_lds(bufA, wf, binit, Sm, nl, hi, w);
        __syncthreads();
        copy_out(UV, Sm, ng, tid, n_nodes);
        __syncthreads();
        if (n1 >= n_groups) break;

        const int n2 = n1 + stride;
        if (n2 < n_groups) load_z(bufA, z, n2, nl, hi, n_nodes);
        compute_to_lds(bufB, wf, binit, Sm, nl, hi, w);
        __syncthreads();
        copy_out(UV, Sm, n1, tid, n_nodes);
        __syncthreads();
        ng = n2;
    }
}

// ---------------- edge scoring ----------------
// score[e] = sum_j relu(u'[src][j] + v[dst][j]) * W2[j] + b2   (u' has b1)
// 16 lanes per edge, 8 edges per lane-group. All 16 gathers issued before
// any compute (sched_barrier fence) -> deep MLP.
static __device__ __forceinline__ float dot8(uint4 u, uint4 v, const float* w) {
    const uint32_t up[4] = { u.x, u.y, u.z, u.w };
    const uint32_t vp[4] = { v.x, v.y, v.z, v.w };
    float s = 0.f;
    #pragma unroll
    for (int p = 0; p < 4; ++p) {
        const float h0 = bf_lo(up[p]) + bf_lo(vp[p]);
        const float h1 = bf_hi(up[p]) + bf_hi(vp[p]);
        s = fmaf(fmaxf(h0, 0.f), w[2 * p], s);
        s = fmaf(fmaxf(h1, 0.f), w[2 * p + 1], s);
    }
    return s;
}
static __device__ __forceinline__ float red16(float s) {
    s += __shfl_xor(s, 1, 64); s += __shfl_xor(s, 2, 64);
    s += __shfl_xor(s, 4, 64); s += __shfl_xor(s, 8, 64);
    return s;
}

#define EPG 8  // edges per 16-lane group

__global__ __launch_bounds__(256, 4) void edge_score(
    const int* __restrict__ ei, const unsigned short* __restrict__ UV,
    const float* __restrict__ W2, const float* __restrict__ b2,
    float* __restrict__ out, int n_edges)
{
    const int g = (blockIdx.x * 256 + threadIdx.x) >> 4;
    const int q = threadIdx.x & 15;
    const int e0 = g * EPG;
    if (e0 >= n_edges) return;

    const float4 w2a = *reinterpret_cast<const float4*>(W2 + q * 8);
    const float4 w2b = *reinterpret_cast<const float4*>(W2 + q * 8 + 4);
    const float wloc[8] = { w2a.x, w2a.y, w2a.z, w2a.w, w2b.x, w2b.y, w2b.z, w2b.w };
    const float bias = b2[0];

    const char* UVb = (const char*)UV;
    const uint32_t qo = (uint32_t)q * 16u;

    if (e0 + EPG - 1 < n_edges) {
        const int4 sA = *reinterpret_cast<const int4*>(ei + e0);
        const int4 sB = *reinterpret_cast<const int4*>(ei + e0 + 4);
        const int4 dA = *reinterpret_cast<const int4*>(ei + n_edges + e0);
        const int4 dB = *reinterpret_cast<const int4*>(ei + n_edges + e0 + 4);
        const int sidx[EPG] = { sA.x, sA.y, sA.z, sA.w, sB.x, sB.y, sB.z, sB.w };
        const int didx[EPG] = { dA.x, dA.y, dA.z, dA.w, dB.x, dB.y, dB.z, dB.w };

        uint4 u[EPG], v[EPG];
        #pragma unroll
        for (int i = 0; i < EPG; ++i) {
            u[i] = *reinterpret_cast<const uint4*>(UVb + ((uint32_t)sidx[i] * 512u + qo));
            v[i] = *reinterpret_cast<const uint4*>(UVb + ((uint32_t)didx[i] * 512u + 256u + qo));
        }
        // Fence: no compute may be hoisted above / loads sunk below.
        __builtin_amdgcn_sched_barrier(0);

        float s[EPG];
        #pragma unroll
        for (int i = 0; i < EPG; ++i) s[i] = dot8(u[i], v[i], wloc);
        #pragma unroll
        for (int i = 0; i < EPG; ++i) s[i] = red16(s[i]) + bias;

        if (q == 0) {
            float4 oA = { s[0], s[1], s[2], s[3] };
            float4 oB = { s[4], s[5], s[6], s[7] };
            *reinterpret_cast<float4*>(out + e0) = oA;
            *reinterpret_cast<float4*>(out + e0 + 4) = oB;
        }
    } else {
        for (int i = 0; i < EPG; ++i) {
            const int e = e0 + i;
            if (e >= n_edges) break;
            const int si = ei[e];
            const int di = ei[n_edges + e];
            const uint4 uu = *reinterpret_cast<const uint4*>(UVb + ((uint32_t)si * 512u + qo));
            const uint4 vv = *reinterpret_cast<const uint4*>(UVb + ((uint32_t)di * 512u + 256u + qo));
            float s = red16(dot8(uu, vv, wloc));
            if (q == 0) out[e] = s + bias;
        }
    }
}

extern "C" void kernel_launch(void* const* d_in, const int* in_sizes, int n_in,
                              void* d_out, int out_size, void* d_ws, size_t ws_size,
                              hipStream_t stream) {
    const float* z  = (const float*)d_in[0];
    const int*   ei = (const int*)d_in[1];
    const float* W1 = (const float*)d_in[2];
    const float* b1 = (const float*)d_in[3];
    const float* W2 = (const float*)d_in[4];
    const float* b2 = (const float*)d_in[5];
    float* out = (float*)d_out;

    const int n_nodes = in_sizes[0] / HIDDEN;
    const int n_edges = in_sizes[1] / 2;

    unsigned short* UV = (unsigned short*)d_ws;  // [n_nodes][256] bf16, b1 folded into u-half

    // Kernel 1: per-node u/v via register-resident-W 32x32x16 MFMA,
    // LDS-staged full-line output stores, 2-deep z prefetch pipeline
    {
        const int n_groups = (n_nodes + 31) / 32;
        const int g1 = n_groups < 512 ? n_groups : 512;
        precompute_mfma32<<<g1, 256, 0, stream>>>(z, W1, b1, UV, n_nodes, n_groups);
    }
    // Kernel 2: per-edge score, 8 edges per 16-lane group, forced-deep MLP
    {
        const int groups = (n_edges + EPG - 1) / EPG;
        const int blocks = (groups * 16 + 255) / 256;
        edge_score<<<blocks, 256, 0, stream>>>(ei, UV, W2, b2, out, n_edges);
    }
}